// Round 7
// baseline (497.339 us; speedup 1.0000x reference)
//
#include <hip/hip_runtime.h>

#define Tv 128

typedef float v2 __attribute__((ext_vector_type(2)));

__device__ __forceinline__ v2 mkv2(float a, float b) { v2 r; r.x = a; r.y = b; return r; }
__device__ __forceinline__ v2 pkfma(v2 a, v2 b, v2 c) {
  return __builtin_elementwise_fma(a, b, c);
}

// ---- DPP / cross-lane helpers (builtins only: convergent + hazard-safe)
template<int CTRL>
__device__ __forceinline__ float dppx(float x) {
  return __int_as_float(__builtin_amdgcn_update_dpp(0, __float_as_int(x), CTRL, 0xF, 0xF, true));
}
__device__ __forceinline__ float dpp_rm(float x, int ctrl, int rm) {
  switch (ctrl) {
    default: return 0.f;
    case 0x111: return __int_as_float(__builtin_amdgcn_update_dpp(0, __float_as_int(x), 0x111, 0xF, 0xF, true));
    case 0x112: return __int_as_float(__builtin_amdgcn_update_dpp(0, __float_as_int(x), 0x112, 0xF, 0xF, true));
    case 0x114: return __int_as_float(__builtin_amdgcn_update_dpp(0, __float_as_int(x), 0x114, 0xF, 0xF, true));
    case 0x118: return __int_as_float(__builtin_amdgcn_update_dpp(0, __float_as_int(x), 0x118, 0xF, 0xF, true));
    case 0x142: return __int_as_float(__builtin_amdgcn_update_dpp(0, __float_as_int(x), 0x142, 0xA, 0xF, true));
    case 0x143: return __int_as_float(__builtin_amdgcn_update_dpp(0, __float_as_int(x), 0x143, 0xC, 0xF, true));
  }
}
// full-wave64 sum, broadcast via readlane(63)
__device__ __forceinline__ float wave_sum(float x) {
  x += dpp_rm(x, 0x111, 0xF);
  x += dpp_rm(x, 0x112, 0xF);
  x += dpp_rm(x, 0x114, 0xF);
  x += dpp_rm(x, 0x118, 0xF);
  x += dpp_rm(x, 0x142, 0xA);
  x += dpp_rm(x, 0x143, 0xC);
  return __int_as_float(__builtin_amdgcn_readlane(__float_as_int(x), 63));
}
template<int M>
__device__ __forceinline__ float lane_xor(float x) {
  if constexpr (M == 1)       return dppx<0xB1>(x);    // quad_perm [1,0,3,2]
  else if constexpr (M == 2)  return dppx<0x4E>(x);    // quad_perm [2,3,0,1]
  else if constexpr (M == 8)  return dppx<0x128>(x);   // row_ror:8 == xor8
  else if constexpr (M == 32) return __shfl_xor(x, 32, 64);
  else return __int_as_float(__builtin_amdgcn_ds_swizzle(__float_as_int(x), (M << 10) | 0x1F));
}
__device__ __forceinline__ float bperm(int addr, float x) {
  return __int_as_float(__builtin_amdgcn_ds_bpermute(addr, __float_as_int(x)));
}
__device__ __forceinline__ float rdlane(float x, int l) {
  return __int_as_float(__builtin_amdgcn_readlane(__float_as_int(x), l));
}
__device__ __forceinline__ float fast_rcp(float x){ return __builtin_amdgcn_rcpf(x); }
__device__ __forceinline__ float fast_rsq(float x){ return __builtin_amdgcn_rsqf(x); }
__device__ __forceinline__ float tanh_(float x){
  float e = __expf(2.0f * x);
  return 1.0f - 2.0f * fast_rcp(e + 1.0f);
}
// row-pair (v2) activations: scalar transcendentals, packed algebra
__device__ __forceinline__ v2 sigm2(v2 x){
  return mkv2(fast_rcp(1.0f + __expf(-x.x)), fast_rcp(1.0f + __expf(-x.y)));
}
__device__ __forceinline__ v2 tanh2(v2 x){
  return mkv2(tanh_(x.x), tanh_(x.y));
}

// butterfly transpose-reduce: returns (per lane) the sum over the 64-lane wave
// of element (L&7) of each thread's 8-vector P2 (packed as v2[4]).
__device__ __forceinline__ float transpose_reduce8(const v2* P2, int L) {
  const int bb0 = L & 1, bb1 = L & 2, bb2 = L & 4;
  float q_[4];
  #pragma unroll
  for (int k = 0; k < 4; k++) {
    float keep = bb0 ? P2[k].y : P2[k].x;
    float send = bb0 ? P2[k].x : P2[k].y;
    q_[k] = keep + lane_xor<1>(send);
  }
  float r_[2];
  #pragma unroll
  for (int k = 0; k < 2; k++) {
    float keep = bb1 ? q_[2 * k + 1] : q_[2 * k];
    float send = bb1 ? q_[2 * k]     : q_[2 * k + 1];
    r_[k] = keep + lane_xor<2>(send);
  }
  float u;
  {
    float keep = bb2 ? r_[1] : r_[0];
    float send = bb2 ? r_[0] : r_[1];
    u = keep + lane_xor<4>(send);
  }
  u += lane_xor<8>(u); u += lane_xor<16>(u); u += lane_xor<32>(u);
  return u;
}

// tan-form lane RY: S[k] += ts * xor_M(S[k]); ts pre-signed per lane.
template<int M>
__device__ __forceinline__ void ry_lane_t(v2* S, float ts) {
  v2 ts2 = mkv2(ts, ts);
  #pragma unroll
  for (int k = 0; k < 4; k++) {
    v2 o;
    o.x = lane_xor<M>(S[k].x);
    o.y = lane_xor<M>(S[k].y);
    S[k] = pkfma(ts2, o, S[k]);
  }
}

// State: 256 amps = 8 regs x 32 lanes, packed as v2 S[4]; s[r] = S[r>>1][r&1].
// q0 -> reg bit2; q1 -> reg bit1; q2 -> reg bit0 (x<->y); q3..q7 -> lane masks 16,8,4,2,1.
// Variational RYs in exact tan(theta/2) form; per-gate (prod cos)^2 -> ct2g on z.
//
// R6 structure: every wave holds ALL 128 rows (2 rows/lane: jA=L, jB=L+64) packed
// as v2 -> proj/emb/epilogue/gates/LSTM fully in-wave; ONLY cross-wave data is
// zbuf (each wave computes 2 of 4 gates) -> ONE barrier/step, zbuf double-buffered.

struct __align__(16) SMem {
  float tt[4][36];    // per gate: tan(theta/2) at [l*8+q], (prod cos)^2 at [32]
  float ipb[8][4];    // (ip_b, in_g, in_b, 0)
  float zbuf[2][32];  // double-buffered by t&1: z[gate][qubit]
};

__global__ __launch_bounds__(128, 2) void qlstm_kernel(
    const float* __restrict__ x,     const float* __restrict__ pe,
    const float* __restrict__ emb_w, const float* __restrict__ emb_b,
    const float* __restrict__ emb_g, const float* __restrict__ emb_bt,
    const float* __restrict__ ip_w,  const float* __restrict__ ip_b,
    const float* __restrict__ in_g,  const float* __restrict__ in_b,
    const float* __restrict__ wq_i,  const float* __restrict__ wq_f,
    const float* __restrict__ wq_gt, const float* __restrict__ wq_o,
    const float* __restrict__ pi_w,  const float* __restrict__ pi_b,
    const float* __restrict__ pf_w,  const float* __restrict__ pf_b,
    const float* __restrict__ pg_w,  const float* __restrict__ pg_b,
    const float* __restrict__ po_w,  const float* __restrict__ po_b,
    const float* __restrict__ on_g,  const float* __restrict__ on_b,
    const float* __restrict__ out_w, const float* __restrict__ out_b,
    float* __restrict__ out)
{
  __shared__ SMem sm;
  const int tid = threadIdx.x;
  const int b   = blockIdx.x;
  const int w   = tid >> 6;             // wave 0/1
  const int L   = tid & 63;
  const int l5  = L & 31;
  const int gate = w * 2 + (L >> 5);    // 0..3 = i,f,g,o (VQC gate split across waves)
  const int o8  = L & 7;
  const int jA  = L, jB = L + 64;       // the two rows this lane owns (both waves identical)

  // ---- stage tan table + per-gate cos-product
  {
    int gg = tid >> 5, rem = tid & 31;
    const float* wsel = (gg == 0) ? wq_i : (gg == 1) ? wq_f : (gg == 2) ? wq_gt : wq_o;
    float th = wsel[rem] * 0.5f;
    float cc = __cosf(th), ss = __sinf(th);
    sm.tt[gg][rem] = ss * fast_rcp(cc);
    float v = cc;
    v *= lane_xor<1>(v); v *= lane_xor<2>(v); v *= lane_xor<4>(v);
    v *= lane_xor<8>(v); v *= lane_xor<16>(v);
    if (rem == 0) sm.tt[gg][32] = v * v;
  }
  if (tid < 8) {
    sm.ipb[tid][0] = ip_b[tid];
    sm.ipb[tid][1] = in_g[tid];
    sm.ipb[tid][2] = in_b[tid];
    sm.ipb[tid][3] = 0.0f;
  }

  // ---- per-thread weights for BOTH rows (v2 = {rowA, rowB})
  v2 EW2[8];
  {
    float4 a0 = *reinterpret_cast<const float4*>(emb_w + jA * 8);
    float4 a1 = *reinterpret_cast<const float4*>(emb_w + jA * 8 + 4);
    float4 b0 = *reinterpret_cast<const float4*>(emb_w + jB * 8);
    float4 b1 = *reinterpret_cast<const float4*>(emb_w + jB * 8 + 4);
    EW2[0] = mkv2(a0.x, b0.x); EW2[1] = mkv2(a0.y, b0.y);
    EW2[2] = mkv2(a0.z, b0.z); EW2[3] = mkv2(a0.w, b0.w);
    EW2[4] = mkv2(a1.x, b1.x); EW2[5] = mkv2(a1.y, b1.y);
    EW2[6] = mkv2(a1.z, b1.z); EW2[7] = mkv2(a1.w, b1.w);
  }
  v2 ebb2 = mkv2(emb_b[jA], emb_b[jB]);
  v2 egg2 = mkv2(emb_g[jA], emb_g[jB]);
  v2 ebt2 = mkv2(emb_bt[jA], emb_bt[jB]);
  // proj weights: packed over output pairs, per row
  v2 IPW1A[4], IPW2A[4], IPW1B[4], IPW2B[4];
  #pragma unroll
  for (int k = 0; k < 4; k++) {
    IPW1A[k] = mkv2(ip_w[(2 * k) * 256 + jA],       ip_w[(2 * k + 1) * 256 + jA]);
    IPW2A[k] = mkv2(ip_w[(2 * k) * 256 + 128 + jA], ip_w[(2 * k + 1) * 256 + 128 + jA]);
    IPW1B[k] = mkv2(ip_w[(2 * k) * 256 + jB],       ip_w[(2 * k + 1) * 256 + jB]);
    IPW2B[k] = mkv2(ip_w[(2 * k) * 256 + 128 + jB], ip_w[(2 * k + 1) * 256 + 128 + jB]);
  }
  // gate weights: per qubit, packed over rows
  v2 GW2[4][8];
  #pragma unroll
  for (int gg = 0; gg < 4; gg++) {
    const float* pw = (gg == 0) ? pi_w : (gg == 1) ? pf_w : (gg == 2) ? pg_w : po_w;
    float4 a0 = *reinterpret_cast<const float4*>(pw + jA * 8);
    float4 a1 = *reinterpret_cast<const float4*>(pw + jA * 8 + 4);
    float4 b0 = *reinterpret_cast<const float4*>(pw + jB * 8);
    float4 b1 = *reinterpret_cast<const float4*>(pw + jB * 8 + 4);
    GW2[gg][0] = mkv2(a0.x, b0.x); GW2[gg][1] = mkv2(a0.y, b0.y);
    GW2[gg][2] = mkv2(a0.z, b0.z); GW2[gg][3] = mkv2(a0.w, b0.w);
    GW2[gg][4] = mkv2(a1.x, b1.x); GW2[gg][5] = mkv2(a1.y, b1.y);
    GW2[gg][6] = mkv2(a1.z, b1.z); GW2[gg][7] = mkv2(a1.w, b1.w);
  }
  v2 gb2[4] = {mkv2(pi_b[jA], pi_b[jB]), mkv2(pf_b[jA], pf_b[jB]),
               mkv2(pg_b[jA], pg_b[jB]), mkv2(po_b[jA], po_b[jB])};
  v2 ong2 = mkv2(on_g[jA], on_g[jB]);
  v2 onb2 = mkv2(on_b[jA], on_b[jB]);
  v2 ow2  = mkv2(out_w[jA], out_w[jB]);
  float outb = out_b[0];
  v2 a2 = ong2 * ow2;

  // Composed per-layer CNOT permutation (verified)
  const int grp = L & 32;
  int aC0, aC1;
  {
    int l1 = l5 ^ ((l5 & 16) >> 1) ^ ((l5 & 4) >> 1);
    int lb = l1 ^ ((l1 & 8) >> 1) ^ ((l1 & 2) >> 1);
    aC0 = (grp | lb) << 2;
    aC1 = (grp | (lb ^ 16)) << 2;
  }

  // measure sign masks (qubit q3..q7 <-> lane bits 16,8,4,2,1): bit set -> -T
  const int sg16 = (l5 & 16) << 27;
  const int sg8  = (l5 & 8)  << 28;
  const int sg4  = (l5 & 4)  << 29;
  const int sg2  = (l5 & 2)  << 30;
  const int sg1  = (l5 & 1)  << 31;
  // RY sign masks: ts = (l5&m) ? +t : -t  -> xor 0x80000000 when bit CLEAR
  const int sR16 = (~l5 & 16) << 27;
  const int sR8  = (~l5 & 8)  << 28;
  const int sR4  = (~l5 & 4)  << 29;
  const int sR2  = (~l5 & 2)  << 30;
  const int sR1  = (~l5 & 1)  << 31;

  v2 h2r = mkv2(0.f, 0.f), c2r = mkv2(0.f, 0.f);
  const float* xbase = x + (size_t)b * Tv * 8;

  __syncthreads();                              // ===== single init barrier (tt/ipb)

  const float4 ipbv = *reinterpret_cast<float4*>(&sm.ipb[o8][0]);
  const float ct2g = sm.tt[gate][32];
  const float* tg = sm.tt[gate];

  // ---- wbar (column sums of emb_w / 128) + bS, fully in-wave
  v2 WB[4]; float bS;
  {
    v2 C8[4];
    #pragma unroll
    for (int k = 0; k < 4; k++)
      C8[k] = mkv2(EW2[2 * k].x + EW2[2 * k].y, EW2[2 * k + 1].x + EW2[2 * k + 1].y);
    float uw = transpose_reduce8(C8, L);        // lane L: colsum(L&7) over 128 rows
    float cs_[8];
    #pragma unroll
    for (int q = 0; q < 8; q++) cs_[q] = rdlane(uw, q) * 0.0078125f;
    WB[0] = mkv2(cs_[0], cs_[1]); WB[1] = mkv2(cs_[2], cs_[3]);
    WB[2] = mkv2(cs_[4], cs_[5]); WB[3] = mkv2(cs_[6], cs_[7]);
    bS = wave_sum(ebb2.x + ebb2.y) * 0.0078125f;
  }
  const float SW = wave_sum(a2.x + a2.y);
  const float KB = wave_sum(onb2.x * ow2.x + onb2.y * ow2.y) + outb;

  // ---- e_0 (fully in-wave)
  v2 e2r;
  {
    float4 q0 = *reinterpret_cast<const float4*>(xbase);
    float4 q1 = *reinterpret_cast<const float4*>(xbase + 4);
    v2 XTv[4] = {mkv2(q0.x, q0.y), mkv2(q0.z, q0.w), mkv2(q1.x, q1.y), mkv2(q1.z, q1.w)};
    v2 er2 = ebb2;
    #pragma unroll
    for (int k = 0; k < 4; k++) {
      er2 = pkfma(mkv2(XTv[k].x, XTv[k].x), EW2[2 * k], er2);
      er2 = pkfma(mkv2(XTv[k].y, XTv[k].y), EW2[2 * k + 1], er2);
    }
    float s2 = wave_sum(er2.x * er2.x + er2.y * er2.y);
    v2 macc = XTv[0] * WB[0];
    macc = pkfma(XTv[1], WB[1], macc);
    macc = pkfma(XTv[2], WB[2], macc);
    macc = pkfma(XTv[3], WB[3], macc);
    float mn = macc.x + macc.y + bS;
    float vr = fmaf(s2, 0.0078125f, -mn * mn);
    float inv = fast_rsq(vr + 1e-5f);
    v2 pe0 = mkv2(pe[jA], pe[jB]);
    e2r = pkfma((er2 - mkv2(mn, mn)) * mkv2(inv, inv), egg2, ebt2) + pe0;
  }

  #pragma unroll 1
  for (int t = 0; t < Tv; t++) {
    // ---- prefetch next x (shared) and pe rows
    v2 XNv[4]; v2 pen2;
    {
      int tn = (t + 1) & (Tv - 1);
      float4 q0 = *reinterpret_cast<const float4*>(xbase + tn * 8);
      float4 q1 = *reinterpret_cast<const float4*>(xbase + tn * 8 + 4);
      XNv[0] = mkv2(q0.x, q0.y); XNv[1] = mkv2(q0.z, q0.w);
      XNv[2] = mkv2(q1.x, q1.y); XNv[3] = mkv2(q1.z, q1.w);
      pen2 = mkv2(pe[tn * 128 + jA], pe[tn * 128 + jB]);
    }

    // ---- proj: fully in-wave (2 rows/lane), butterfly transpose-reduce
    const v2 eAs = mkv2(e2r.x, e2r.x), eBs = mkv2(e2r.y, e2r.y);
    const v2 hAs = mkv2(h2r.x, h2r.x), hBs = mkv2(h2r.y, h2r.y);
    v2 V[4];
    #pragma unroll
    for (int k = 0; k < 4; k++) {
      v2 acc = hBs * IPW2B[k];
      acc = pkfma(eBs, IPW1B[k], acc);
      acc = pkfma(hAs, IPW2A[k], acc);
      acc = pkfma(eAs, IPW1A[k], acc);
      V[k] = acc;
    }
    float u = transpose_reduce8(V, L);           // complete over all 128 rows

    // ---- angles: tanh + LN(8) -> encode factors, broadcast via readlane
    float tv = tanh_(u + ipbv.x);
    float m1 = tv, m2 = tv * tv;
    m1 += lane_xor<1>(m1); m2 += lane_xor<1>(m2);
    m1 += lane_xor<2>(m1); m2 += lane_xor<2>(m2);
    m1 += lane_xor<4>(m1); m2 += lane_xor<4>(m2);
    float pm = m1 * 0.125f;
    float pv = fmaf(m2, 0.125f, -pm * pm);
    float theta = (tv - pm) * fast_rsq(pv + 1e-5f) * ipbv.y + ipbv.z;
    float ph = theta * 0.5f;
    float cE = __cosf(ph), sE = __sinf(ph);
    float fm = cE - sE, fp = cE + sE;
    float f_[16];
    #pragma unroll
    for (int qq = 0; qq < 8; qq++) {
      f_[2 * qq]     = rdlane(fm, qq);
      f_[2 * qq + 1] = rdlane(fp, qq);
    }

    // ---- VQC encode (constant-indexed)
    v2 S[4];
    {
      float g01_[4];
      #pragma unroll
      for (int i = 0; i < 4; i++)
        g01_[i] = f_[(i >> 1) & 1] * f_[2 + (i & 1)];
      float s3 = (l5 & 16) ? f_[7]  : f_[6];
      float s4 = (l5 & 8)  ? f_[9]  : f_[8];
      float s5 = (l5 & 4)  ? f_[11] : f_[10];
      float s6 = (l5 & 2)  ? f_[13] : f_[12];
      float s7 = (l5 & 1)  ? f_[15] : f_[14];
      float lf = s3 * s4 * s5 * s6 * s7 * 0.0625f;
      const v2 F45 = mkv2(f_[4], f_[5]);
      #pragma unroll
      for (int k = 0; k < 4; k++) {
        float tk = lf * g01_[k];
        S[k] = mkv2(tk, tk) * F45;
      }
    }

    // ---- 4 variational layers; tan values read from LDS per layer (reg relief)
    #pragma unroll
    for (int l = 0; l < 4; l++) {
      float4 qa = *reinterpret_cast<const float4*>(tg + l * 8);
      float4 qb = *reinterpret_cast<const float4*>(tg + l * 8 + 4);
      v2 N0, N1, N2, N3;
      N0.x = bperm(aC0, S[0].x); N0.y = bperm(aC1, S[0].y);
      N1.x = bperm(aC1, S[1].y); N1.y = bperm(aC0, S[1].x);
      N2.x = bperm(aC0, S[3].x); N2.y = bperm(aC1, S[3].y);
      N3.x = bperm(aC1, S[2].y); N3.y = bperm(aC0, S[2].x);
      S[0] = N0; S[1] = N1; S[2] = N2; S[3] = N3;
      // q0: S[k] <-> S[k+2]
      {
        v2 t0 = mkv2(qa.x, qa.x);
        v2 a0 = S[0], a1 = S[1];
        S[0] = pkfma(-t0, S[2], S[0]);
        S[2] = pkfma( t0, a0,  S[2]);
        S[1] = pkfma(-t0, S[3], S[1]);
        S[3] = pkfma( t0, a1,  S[3]);
      }
      // q1: S[k] <-> S[k+1]
      {
        v2 t1 = mkv2(qa.y, qa.y);
        v2 a0 = S[0], a2 = S[2];
        S[0] = pkfma(-t1, S[1], S[0]);
        S[1] = pkfma( t1, a0,  S[1]);
        S[2] = pkfma(-t1, S[3], S[2]);
        S[3] = pkfma( t1, a2,  S[3]);
      }
      // q2: x <-> y
      {
        v2 nts = mkv2(-qa.z, qa.z);
        #pragma unroll
        for (int k = 0; k < 4; k++) {
          v2 aa = S[k];
          v2 sw = __builtin_shufflevector(aa, aa, 1, 0);
          S[k] = pkfma(nts, sw, aa);
        }
      }
      // q3..q7: lane RYs with per-lane pre-signed t (sign via xor mask)
      ry_lane_t<16>(S, __int_as_float(__float_as_int(qa.w) ^ sR16));
      ry_lane_t<8> (S, __int_as_float(__float_as_int(qb.x) ^ sR8));
      ry_lane_t<4> (S, __int_as_float(__float_as_int(qb.y) ^ sR4));
      ry_lane_t<2> (S, __int_as_float(__float_as_int(qb.z) ^ sR2));
      ry_lane_t<1> (S, __int_as_float(__float_as_int(qb.w) ^ sR1));
    }

    // ---- measure: signed 8-vector, one butterfly transpose-reduce (R5-verified)
    {
      v2 P[4];
      #pragma unroll
      for (int k = 0; k < 4; k++) P[k] = S[k] * S[k];
      v2 A = P[0] + P[2];
      v2 B = P[1] + P[3];
      v2 D = (P[0] - P[2]) + (P[1] - P[3]);
      v2 Ev = A - B;
      v2 G = A + B;
      float z0p = D.x + D.y;
      float z1p = Ev.x + Ev.y;
      float z2p = G.x - G.y;
      float T = G.x + G.y;
      int Ti = __float_as_int(T);
      v2 ZP[4];
      ZP[0] = mkv2(z0p, z1p);
      ZP[1] = mkv2(z2p, __int_as_float(Ti ^ sg16));
      ZP[2] = mkv2(__int_as_float(Ti ^ sg8), __int_as_float(Ti ^ sg4));
      ZP[3] = mkv2(__int_as_float(Ti ^ sg2), __int_as_float(Ti ^ sg1));
      const int cb0 = l5 & 1, cb1 = l5 & 2, cb2 = l5 & 4;
      float mq[4];
      #pragma unroll
      for (int k = 0; k < 4; k++) {
        float keep = cb0 ? ZP[k].y : ZP[k].x;
        float send = cb0 ? ZP[k].x : ZP[k].y;
        mq[k] = keep + lane_xor<1>(send);
      }
      float mr[2];
      #pragma unroll
      for (int k = 0; k < 2; k++) {
        float keep = cb1 ? mq[2 * k + 1] : mq[2 * k];
        float send = cb1 ? mq[2 * k]     : mq[2 * k + 1];
        mr[k] = keep + lane_xor<2>(send);
      }
      float zu;
      {
        float keep = cb2 ? mr[1] : mr[0];
        float send = cb2 ? mr[0] : mr[1];
        zu = keep + lane_xor<4>(send);
      }
      zu += lane_xor<8>(zu);
      zu += lane_xor<16>(zu);
      if (l5 < 8) sm.zbuf[t & 1][gate * 8 + l5] = zu * ct2g;
    }

    // ---- next-step emb (fully in-wave; independent of zbuf)
    v2 en_raw2 = ebb2;
    #pragma unroll
    for (int k = 0; k < 4; k++) {
      en_raw2 = pkfma(mkv2(XNv[k].x, XNv[k].x), EW2[2 * k], en_raw2);
      en_raw2 = pkfma(mkv2(XNv[k].y, XNv[k].y), EW2[2 * k + 1], en_raw2);
    }
    float s2n = wave_sum(en_raw2.x * en_raw2.x + en_raw2.y * en_raw2.y);

    __syncthreads();                              // ===== THE barrier: zbuf[t&1] ready

    // ---- gate projections + LSTM (both rows, packed)
    const float* zb = sm.zbuf[t & 1];
    v2 acg2[4];
    #pragma unroll
    for (int gg = 0; gg < 4; gg++) {
      float4 za0 = *reinterpret_cast<const float4*>(zb + gg * 8);
      float4 za1 = *reinterpret_cast<const float4*>(zb + gg * 8 + 4);
      v2 a = gb2[gg];
      a = pkfma(mkv2(za0.x, za0.x), GW2[gg][0], a);
      a = pkfma(mkv2(za0.y, za0.y), GW2[gg][1], a);
      a = pkfma(mkv2(za0.z, za0.z), GW2[gg][2], a);
      a = pkfma(mkv2(za0.w, za0.w), GW2[gg][3], a);
      a = pkfma(mkv2(za1.x, za1.x), GW2[gg][4], a);
      a = pkfma(mkv2(za1.y, za1.y), GW2[gg][5], a);
      a = pkfma(mkv2(za1.z, za1.z), GW2[gg][6], a);
      a = pkfma(mkv2(za1.w, za1.w), GW2[gg][7], a);
      acg2[gg] = a;
    }
    v2 it2 = sigm2(acg2[0]), ft2 = sigm2(acg2[1]);
    v2 gt2 = tanh2(acg2[2]), ot2 = sigm2(acg2[3]);
    c2r = pkfma(ft2, c2r, it2 * gt2);
    h2r = ot2 * tanh2(c2r);

    // ---- e_{t+1}: linear mean + in-wave variance (both rows packed)
    v2 en2;
    {
      v2 macc = XNv[0] * WB[0];
      macc = pkfma(XNv[1], WB[1], macc);
      macc = pkfma(XNv[2], WB[2], macc);
      macc = pkfma(XNv[3], WB[3], macc);
      float mn = macc.x + macc.y + bS;
      float vr = fmaf(s2n, 0.0078125f, -mn * mn);
      float inv = fast_rsq(vr + 1e-5f);
      en2 = pkfma((en_raw2 - mkv2(mn, mn)) * mkv2(inv, inv), egg2, ebt2) + pen2;
    }

    // ---- output epilogue for step t (fully in-wave; store by one thread)
    {
      v2 y2 = h2r + e2r;
      float sy  = wave_sum(y2.x + y2.y);
      float syy = wave_sum(y2.x * y2.x + y2.y * y2.y);
      float sya = wave_sum(y2.x * a2.x + y2.y * a2.y);
      if (tid == 0) {
        float mo = sy * 0.0078125f;
        float vo = fmaf(syy, 0.0078125f, -mo * mo);
        float io = fast_rsq(vo + 1e-5f);
        out[b * Tv + t] = fmaf(io, sya - mo * SW, KB);
      }
    }
    e2r = en2;
  }
}

extern "C" void kernel_launch(void* const* d_in, const int* in_sizes, int n_in,
                              void* d_out, int out_size, void* d_ws, size_t ws_size,
                              hipStream_t stream) {
  qlstm_kernel<<<dim3(1024), dim3(128), 0, stream>>>(
      (const float*)d_in[0],  (const float*)d_in[1],  (const float*)d_in[2],  (const float*)d_in[3],
      (const float*)d_in[4],  (const float*)d_in[5],  (const float*)d_in[6],  (const float*)d_in[7],
      (const float*)d_in[8],  (const float*)d_in[9],  (const float*)d_in[10], (const float*)d_in[11],
      (const float*)d_in[12], (const float*)d_in[13], (const float*)d_in[14], (const float*)d_in[15],
      (const float*)d_in[16], (const float*)d_in[17], (const float*)d_in[18], (const float*)d_in[19],
      (const float*)d_in[20], (const float*)d_in[21], (const float*)d_in[22], (const float*)d_in[23],
      (const float*)d_in[24], (const float*)d_in[25],
      (float*)d_out);
}

// Round 8
// 476.899 us; speedup vs baseline: 1.0429x; 1.0429x over previous
//
#include <hip/hip_runtime.h>

#define Tv 128

typedef float v2 __attribute__((ext_vector_type(2)));

__device__ __forceinline__ v2 pkfma(v2 a, v2 b, v2 c) {
  return __builtin_elementwise_fma(a, b, c);
}

// ---- DPP / cross-lane helpers (builtins only: convergent + hazard-safe)
template<int CTRL>
__device__ __forceinline__ float dppx(float x) {
  return __int_as_float(__builtin_amdgcn_update_dpp(0, __float_as_int(x), CTRL, 0xF, 0xF, true));
}
__device__ __forceinline__ float dpp_rm(float x, int ctrl, int rm) {
  switch (ctrl) {
    default: return 0.f;
    case 0x111: return __int_as_float(__builtin_amdgcn_update_dpp(0, __float_as_int(x), 0x111, 0xF, 0xF, true));
    case 0x112: return __int_as_float(__builtin_amdgcn_update_dpp(0, __float_as_int(x), 0x112, 0xF, 0xF, true));
    case 0x114: return __int_as_float(__builtin_amdgcn_update_dpp(0, __float_as_int(x), 0x114, 0xF, 0xF, true));
    case 0x118: return __int_as_float(__builtin_amdgcn_update_dpp(0, __float_as_int(x), 0x118, 0xF, 0xF, true));
    case 0x142: return __int_as_float(__builtin_amdgcn_update_dpp(0, __float_as_int(x), 0x142, 0xA, 0xF, true));
    case 0x143: return __int_as_float(__builtin_amdgcn_update_dpp(0, __float_as_int(x), 0x143, 0xC, 0xF, true));
  }
}
// full-wave64 sum, broadcast via readlane(63)
__device__ __forceinline__ float wave_sum(float x) {
  x += dpp_rm(x, 0x111, 0xF);
  x += dpp_rm(x, 0x112, 0xF);
  x += dpp_rm(x, 0x114, 0xF);
  x += dpp_rm(x, 0x118, 0xF);
  x += dpp_rm(x, 0x142, 0xA);
  x += dpp_rm(x, 0x143, 0xC);
  return __int_as_float(__builtin_amdgcn_readlane(__float_as_int(x), 63));
}
template<int M>
__device__ __forceinline__ float lane_xor(float x) {
  if constexpr (M == 1)       return dppx<0xB1>(x);    // quad_perm [1,0,3,2]
  else if constexpr (M == 2)  return dppx<0x4E>(x);    // quad_perm [2,3,0,1]
  else if constexpr (M == 8)  return dppx<0x128>(x);   // row_ror:8 == xor8
  else if constexpr (M == 32) return __shfl_xor(x, 32, 64);
  else return __int_as_float(__builtin_amdgcn_ds_swizzle(__float_as_int(x), (M << 10) | 0x1F));
}
__device__ __forceinline__ float bperm(int addr, float x) {
  return __int_as_float(__builtin_amdgcn_ds_bpermute(addr, __float_as_int(x)));
}
__device__ __forceinline__ float rdlane(float x, int l) {
  return __int_as_float(__builtin_amdgcn_readlane(__float_as_int(x), l));
}
__device__ __forceinline__ float fast_rcp(float x){ return __builtin_amdgcn_rcpf(x); }
__device__ __forceinline__ float fast_rsq(float x){ return __builtin_amdgcn_rsqf(x); }
__device__ __forceinline__ float tanh_(float x){
  float e = __expf(2.0f * x);
  return 1.0f - 2.0f * fast_rcp(e + 1.0f);
}
__device__ __forceinline__ float sigm_(float x){
  return fast_rcp(1.0f + __expf(-x));
}

// butterfly transpose-reduce: returns (per lane) the sum over the 64-lane wave
// of element (L&7) of each thread's 8-vector P2 (packed as v2[4]).
__device__ __forceinline__ float transpose_reduce8(const v2* P2, int L) {
  const int bb0 = L & 1, bb1 = L & 2, bb2 = L & 4;
  float q_[4];
  #pragma unroll
  for (int k = 0; k < 4; k++) {
    float keep = bb0 ? P2[k].y : P2[k].x;
    float send = bb0 ? P2[k].x : P2[k].y;
    q_[k] = keep + lane_xor<1>(send);
  }
  float r_[2];
  #pragma unroll
  for (int k = 0; k < 2; k++) {
    float keep = bb1 ? q_[2 * k + 1] : q_[2 * k];
    float send = bb1 ? q_[2 * k]     : q_[2 * k + 1];
    r_[k] = keep + lane_xor<2>(send);
  }
  float u;
  {
    float keep = bb2 ? r_[1] : r_[0];
    float send = bb2 ? r_[0] : r_[1];
    u = keep + lane_xor<4>(send);
  }
  u += lane_xor<8>(u); u += lane_xor<16>(u); u += lane_xor<32>(u);
  return u;
}

// tan-form lane RY: S[k] += ts * xor_M(S[k]); ts pre-signed per lane.
template<int M>
__device__ __forceinline__ void ry_lane_t(v2* S, float ts) {
  v2 ts2 = {ts, ts};
  #pragma unroll
  for (int k = 0; k < 4; k++) {
    v2 o;
    o.x = lane_xor<M>(S[k].x);
    o.y = lane_xor<M>(S[k].y);
    S[k] = pkfma(ts2, o, S[k]);
  }
}

// State: 256 amps = 8 regs x 32 lanes, packed as v2 S[4]; s[r] = S[r>>1][r&1].
// q0 -> reg bit2; q1 -> reg bit1; q2 -> reg bit0 (x<->y); q3..q7 -> lane masks 16,8,4,2,1.
// Variational RYs in exact tan(theta/2) form (sequential, R1-verified);
// per-gate (prod cos)^2 applied once to the quadratic z measurements (ct2g).

struct __align__(16) SMem {
  float tt[4][36];    // per gate: tan(theta/2) at [l*8+q], (prod cos)^2 at [32]
  float ipb[8][4];    // (ip_b, in_g*0.5, in_b*0.5, 0)  -> theta/2 computed directly
  float zbuf[32];     // z[gate][qubit]
  float embp[2][2];   // emb partials
  float projp[2][8];  // proj partials (init: wbar partials)
  float outp[2][4];   // out-epilogue partials (init: SW/KB)
};

__global__ __launch_bounds__(128, 2) void qlstm_kernel(
    const float* __restrict__ x,     const float* __restrict__ pe,
    const float* __restrict__ emb_w, const float* __restrict__ emb_b,
    const float* __restrict__ emb_g, const float* __restrict__ emb_bt,
    const float* __restrict__ ip_w,  const float* __restrict__ ip_b,
    const float* __restrict__ in_g,  const float* __restrict__ in_b,
    const float* __restrict__ wq_i,  const float* __restrict__ wq_f,
    const float* __restrict__ wq_gt, const float* __restrict__ wq_o,
    const float* __restrict__ pi_w,  const float* __restrict__ pi_b,
    const float* __restrict__ pf_w,  const float* __restrict__ pf_b,
    const float* __restrict__ pg_w,  const float* __restrict__ pg_b,
    const float* __restrict__ po_w,  const float* __restrict__ po_b,
    const float* __restrict__ on_g,  const float* __restrict__ on_b,
    const float* __restrict__ out_w, const float* __restrict__ out_b,
    float* __restrict__ out)
{
  __shared__ SMem sm;
  const int tid = threadIdx.x;          // 0..127 = row j
  const int b   = blockIdx.x;
  const int w   = tid >> 6;             // wave 0/1
  const int L   = tid & 63;
  const int l5  = L & 31;
  const int gate = w * 2 + (L >> 5);    // 0..3 = i,f,g,o
  const int o8  = L & 7;

  // ---- stage tan table + per-gate cos-product
  {
    int gg = tid >> 5, rem = tid & 31;
    const float* wsel = (gg == 0) ? wq_i : (gg == 1) ? wq_f : (gg == 2) ? wq_gt : wq_o;
    float th = wsel[rem] * 0.5f;
    float cc = __cosf(th), ss = __sinf(th);
    sm.tt[gg][rem] = ss * fast_rcp(cc);
    float v = cc;
    v *= lane_xor<1>(v); v *= lane_xor<2>(v); v *= lane_xor<4>(v);
    v *= lane_xor<8>(v); v *= lane_xor<16>(v);
    if (rem == 0) sm.tt[gg][32] = v * v;
  }
  if (tid < 8) {
    sm.ipb[tid][0] = ip_b[tid];
    sm.ipb[tid][1] = in_g[tid] * 0.5f;
    sm.ipb[tid][2] = in_b[tid] * 0.5f;
    sm.ipb[tid][3] = 0.0f;
  }

  // ---- persistent per-thread weights (row j = tid)
  const int j = tid;
  v2 EW[4];
  {
    float4 a = *reinterpret_cast<const float4*>(emb_w + j * 8);
    float4 c = *reinterpret_cast<const float4*>(emb_w + j * 8 + 4);
    EW[0] = {a.x, a.y}; EW[1] = {a.z, a.w}; EW[2] = {c.x, c.y}; EW[3] = {c.z, c.w};
  }
  float ebb = emb_b[j], egg = emb_g[j], ebt = emb_bt[j];
  v2 IPW1[4], IPW2[4];
  #pragma unroll
  for (int k = 0; k < 4; k++) {
    IPW1[k] = {ip_w[(2 * k) * 256 + j],       ip_w[(2 * k + 1) * 256 + j]};
    IPW2[k] = {ip_w[(2 * k) * 256 + 128 + j], ip_w[(2 * k + 1) * 256 + 128 + j]};
  }
  v2 GW[4][4];
  #pragma unroll
  for (int gg = 0; gg < 4; gg++) {
    const float* pw = (gg == 0) ? pi_w : (gg == 1) ? pf_w : (gg == 2) ? pg_w : po_w;
    float4 a = *reinterpret_cast<const float4*>(pw + j * 8);
    float4 c = *reinterpret_cast<const float4*>(pw + j * 8 + 4);
    GW[gg][0] = {a.x, a.y}; GW[gg][1] = {a.z, a.w};
    GW[gg][2] = {c.x, c.y}; GW[gg][3] = {c.z, c.w};
  }
  float gb[4] = {pi_b[j], pf_b[j], pg_b[j], po_b[j]};
  float ong = on_g[j], onb = on_b[j], ow_ = out_w[j];
  float outb = out_b[0];
  float a_ = ong * ow_;

  // Composed per-layer CNOT permutation (verified R4)
  const int grp = L & 32;
  int aC0, aC1;
  {
    int l1 = l5 ^ ((l5 & 16) >> 1) ^ ((l5 & 4) >> 1);
    int lb = l1 ^ ((l1 & 8) >> 1) ^ ((l1 & 2) >> 1);
    aC0 = (grp | lb) << 2;
    aC1 = (grp | (lb ^ 16)) << 2;
  }

  // sign masks for measure (qubit q3..q7 <-> lane bits 16,8,4,2,1): bit set -> -T
  const int sg16 = (l5 & 16) << 27;
  const int sg8  = (l5 & 8)  << 28;
  const int sg4  = (l5 & 4)  << 29;
  const int sg2  = (l5 & 2)  << 30;
  const int sg1  = (l5 & 1)  << 31;

  float h = 0.f, c = 0.f;
  const float* xbase = x + (size_t)b * Tv * 8;

  // ---- init: column-sum of emb_w (wbar) + sum of emb_b, for linear mean
  {
    float uw = transpose_reduce8(EW, L);
    float eb1 = wave_sum(ebb);
    if (L < 8) sm.projp[w][L] = uw;
    if (L == 0) sm.embp[w][0] = eb1;
  }
  __syncthreads();                              // ===== init barrier A

  // ---- loop-invariant register hoists (LDS -> VGPR, once)
  v2 WB[4]; float bS;
  {
    #pragma unroll
    for (int k = 0; k < 4; k++) {
      WB[k].x = (sm.projp[0][2 * k]     + sm.projp[1][2 * k])     * 0.0078125f;
      WB[k].y = (sm.projp[0][2 * k + 1] + sm.projp[1][2 * k + 1]) * 0.0078125f;
    }
    bS = (sm.embp[0][0] + sm.embp[1][0]) * 0.0078125f;
  }
  float4 ipbv = *reinterpret_cast<float4*>(&sm.ipb[o8][0]);
  v2 LT0[4], LT1[4], LNTS[4];
  float LTS[4][5];
  float ct2g = sm.tt[gate][32];
  {
    const float* tg = sm.tt[gate];
    #pragma unroll
    for (int l = 0; l < 4; l++) {
      float4 qa = *reinterpret_cast<const float4*>(tg + l * 8);
      float4 qb = *reinterpret_cast<const float4*>(tg + l * 8 + 4);
      LT0[l]  = {qa.x, qa.x};
      LT1[l]  = {qa.y, qa.y};
      LNTS[l] = {-qa.z, qa.z};
      float tq[5] = {qa.w, qb.x, qb.y, qb.z, qb.w};
      #pragma unroll
      for (int q = 0; q < 5; q++) {
        int m = 16 >> q;
        LTS[l][q] = (l5 & m) ? tq[q] : -tq[q];
      }
    }
  }

  // ---- pre-loop: e_0 + SW/KB partials
  float e;
  {
    float4 a = *reinterpret_cast<const float4*>(xbase);
    float4 cq = *reinterpret_cast<const float4*>(xbase + 4);
    v2 XT[4] = {{a.x,a.y},{a.z,a.w},{cq.x,cq.y},{cq.z,cq.w}};
    v2 acc = XT[0] * EW[0];
    acc = pkfma(XT[1], EW[1], acc);
    acc = pkfma(XT[2], EW[2], acc);
    acc = pkfma(XT[3], EW[3], acc);
    float er = ebb + acc.x + acc.y;
    float s2 = wave_sum(er * er);
    float r0 = wave_sum(a_), r1 = wave_sum(onb * ow_);
    if (L == 0) {
      sm.embp[w][1] = s2;
      sm.outp[w][0] = r0; sm.outp[w][1] = r1;
    }
    __syncthreads();                            // ===== init barrier B
    v2 mac = XT[0] * WB[0];
    mac = pkfma(XT[1], WB[1], mac);
    mac = pkfma(XT[2], WB[2], mac);
    mac = pkfma(XT[3], WB[3], mac);
    float mn = mac.x + mac.y + bS;
    float s2t = sm.embp[0][1] + sm.embp[1][1];
    float vr = fmaf(s2t, 0.0078125f, -mn * mn);
    float inv = fast_rsq(vr + 1e-5f);
    e = (er - mn) * inv * egg + ebt + pe[j];
  }
  const float SW = sm.outp[0][0] + sm.outp[1][0];
  const float KB = sm.outp[0][1] + sm.outp[1][1] + outb;

  #pragma unroll 1
  for (int t = 0; t < Tv; t++) {
    // ---- prefetch next x,pe
    v2 XN[4]; float pen;
    {
      int tn = (t + 1) & (Tv - 1);
      float4 a = *reinterpret_cast<const float4*>(xbase + tn * 8);
      float4 cq = *reinterpret_cast<const float4*>(xbase + tn * 8 + 4);
      XN[0] = {a.x,a.y}; XN[1] = {a.z,a.w}; XN[2] = {cq.x,cq.y}; XN[3] = {cq.z,cq.w};
      pen = pe[tn * 128 + j];
    }

    // ---- proj: p_o = e*ipw1[o] + h*ipw2[o] (packed), butterfly transpose-reduce
    const v2 e2 = {e, e}, h2 = {h, h};
    v2 P2[4];
    #pragma unroll
    for (int k = 0; k < 4; k++)
      P2[k] = pkfma(e2, IPW1[k], h2 * IPW2[k]);
    float u = transpose_reduce8(P2, L);
    if (L < 8) sm.projp[w][L] = u;
    __syncthreads();                                  // ===== barrier 1
    u += sm.projp[1 - w][o8];
    if (t && tid == 0) {                              // emit out[t-1] (pipelined)
      float sy  = sm.outp[0][0] + sm.outp[1][0];
      float sy2 = sm.outp[0][1] + sm.outp[1][1];
      float sya = sm.outp[0][2] + sm.outp[1][2];
      float mn2 = sy * 0.0078125f;
      float vr2 = fmaf(sy2, 0.0078125f, -mn2 * mn2);
      float inv2 = fast_rsq(vr2 + 1e-5f);
      out[b * Tv + t - 1] = fmaf(inv2, sya - mn2 * SW, KB);
    }

    // ---- angles: tanh + LN(8) -> half-angle directly (ipb pre-scaled by 0.5)
    float tv = tanh_(u + ipbv.x);
    float m1 = tv, m2 = tv * tv;
    m1 += lane_xor<1>(m1); m2 += lane_xor<1>(m2);
    m1 += lane_xor<2>(m1); m2 += lane_xor<2>(m2);
    m1 += lane_xor<4>(m1); m2 += lane_xor<4>(m2);
    float pm = m1 * 0.125f;
    float pv = fmaf(m2, 0.125f, -pm * pm);
    float ph = (tv - pm) * fast_rsq(pv + 1e-5f) * ipbv.y + ipbv.z;
    float cE = __cosf(ph), sE = __sinf(ph);
    float fm = cE - sE, fp = cE + sE;
    float f_[16];
    #pragma unroll
    for (int qq = 0; qq < 8; qq++) {
      f_[2 * qq]     = rdlane(fm, qq);
      f_[2 * qq + 1] = rdlane(fp, qq);
    }

    // ---- VQC encode (packed); all f_ reads constant-indexed (no scratch risk)
    v2 S[4];
    {
      float g01_[4];
      #pragma unroll
      for (int i = 0; i < 4; i++)
        g01_[i] = f_[(i >> 1) & 1] * f_[2 + (i & 1)];
      float s3 = (l5 & 16) ? f_[7]  : f_[6];
      float s4 = (l5 & 8)  ? f_[9]  : f_[8];
      float s5 = (l5 & 4)  ? f_[11] : f_[10];
      float s6 = (l5 & 2)  ? f_[13] : f_[12];
      float s7 = (l5 & 1)  ? f_[15] : f_[14];
      float lf = s3 * s4 * s5 * s6 * s7 * 0.0625f;
      const v2 F45 = {f_[4], f_[5]};
      #pragma unroll
      for (int k = 0; k < 4; k++) {
        float tk = lf * g01_[k];
        v2 tk2 = {tk, tk};
        S[k] = tk2 * F45;
      }
    }

    // ---- 4 variational layers: composed bpermute + 8 tan-form RYs each (R1-exact)
    #pragma unroll
    for (int l = 0; l < 4; l++) {
      v2 N0, N1, N2, N3;
      N0.x = bperm(aC0, S[0].x); N0.y = bperm(aC1, S[0].y);
      N1.x = bperm(aC1, S[1].y); N1.y = bperm(aC0, S[1].x);
      N2.x = bperm(aC0, S[3].x); N2.y = bperm(aC1, S[3].y);
      N3.x = bperm(aC1, S[2].y); N3.y = bperm(aC0, S[2].x);
      S[0] = N0; S[1] = N1; S[2] = N2; S[3] = N3;
      // q0: S[k] <-> S[k+2]
      {
        v2 t0 = LT0[l];
        v2 a0 = S[0], a1 = S[1];
        S[0] = pkfma(-t0, S[2], S[0]);
        S[2] = pkfma( t0, a0,  S[2]);
        S[1] = pkfma(-t0, S[3], S[1]);
        S[3] = pkfma( t0, a1,  S[3]);
      }
      // q1: S[k] <-> S[k+1]
      {
        v2 t1 = LT1[l];
        v2 a0 = S[0], a2 = S[2];
        S[0] = pkfma(-t1, S[1], S[0]);
        S[1] = pkfma( t1, a0,  S[1]);
        S[2] = pkfma(-t1, S[3], S[2]);
        S[3] = pkfma( t1, a2,  S[3]);
      }
      // q2: x <-> y
      {
        v2 nts = LNTS[l];
        #pragma unroll
        for (int k = 0; k < 4; k++) {
          v2 aa = S[k];
          v2 sw = __builtin_shufflevector(aa, aa, 1, 0);
          S[k] = pkfma(nts, sw, aa);
        }
      }
      // q3..q7: lane RYs
      ry_lane_t<16>(S, LTS[l][0]);
      ry_lane_t<8>(S, LTS[l][1]);
      ry_lane_t<4>(S, LTS[l][2]);
      ry_lane_t<2>(S, LTS[l][3]);
      ry_lane_t<1>(S, LTS[l][4]);
    }

    // ---- measure: per-lane signed 8-vector, one 32-lane butterfly transpose-reduce
    // V = (z0p, z1p, z2p, +/-T x5); lane l5 ends with z_{l5&7} for its gate.
    {
      v2 P[4];
      #pragma unroll
      for (int k = 0; k < 4; k++) P[k] = S[k] * S[k];
      v2 A = P[0] + P[2];
      v2 B = P[1] + P[3];
      v2 D = (P[0] - P[2]) + (P[1] - P[3]);
      v2 Ev = A - B;
      v2 G = A + B;
      float z0p = D.x + D.y;            // q0 sign: reg bit2
      float z1p = Ev.x + Ev.y;          // q1 sign: reg bit1
      float z2p = G.x - G.y;            // q2 sign: x/y
      float T = G.x + G.y;              // total lane prob
      int Ti = __float_as_int(T);
      v2 ZP[4];
      ZP[0] = {z0p, z1p};
      ZP[1] = {z2p, __int_as_float(Ti ^ sg16)};
      ZP[2] = {__int_as_float(Ti ^ sg8), __int_as_float(Ti ^ sg4)};
      ZP[3] = {__int_as_float(Ti ^ sg2), __int_as_float(Ti ^ sg1)};
      const int cb0 = l5 & 1, cb1 = l5 & 2, cb2 = l5 & 4;
      float mq[4];
      #pragma unroll
      for (int k = 0; k < 4; k++) {
        float keep = cb0 ? ZP[k].y : ZP[k].x;
        float send = cb0 ? ZP[k].x : ZP[k].y;
        mq[k] = keep + lane_xor<1>(send);
      }
      float mr[2];
      #pragma unroll
      for (int k = 0; k < 2; k++) {
        float keep = cb1 ? mq[2 * k + 1] : mq[2 * k];
        float send = cb1 ? mq[2 * k]     : mq[2 * k + 1];
        mr[k] = keep + lane_xor<2>(send);
      }
      float zu;
      {
        float keep = cb2 ? mr[1] : mr[0];
        float send = cb2 ? mr[0] : mr[1];
        zu = keep + lane_xor<4>(send);
      }
      zu += lane_xor<8>(zu);
      zu += lane_xor<16>(zu);
      if (l5 < 8) sm.zbuf[gate * 8 + l5] = zu * ct2g;
    }

    // ---- next-step emb s2 partial (recurrence-independent; rides barrier 2)
    v2 acc = XN[0] * EW[0];
    acc = pkfma(XN[1], EW[1], acc);
    acc = pkfma(XN[2], EW[2], acc);
    acc = pkfma(XN[3], EW[3], acc);
    float en_raw = ebb + acc.x + acc.y;
    {
      float s2n = wave_sum(en_raw * en_raw);
      if (L == 0) sm.embp[w][0] = s2n;
    }
    __syncthreads();                                  // ===== barrier 2

    // ---- gate projections + LSTM cell (packed dot products)
    float acg[4];
    #pragma unroll
    for (int gg = 0; gg < 4; gg++) {
      float4 za0 = *reinterpret_cast<float4*>(&sm.zbuf[gg * 8]);
      float4 za1 = *reinterpret_cast<float4*>(&sm.zbuf[gg * 8 + 4]);
      v2 Z0 = {za0.x, za0.y}, Z1 = {za0.z, za0.w};
      v2 Z2 = {za1.x, za1.y}, Z3 = {za1.z, za1.w};
      v2 av = Z0 * GW[gg][0];
      av = pkfma(Z1, GW[gg][1], av);
      av = pkfma(Z2, GW[gg][2], av);
      av = pkfma(Z3, GW[gg][3], av);
      acg[gg] = gb[gg] + av.x + av.y;
    }
    float it = sigm_(acg[0]), ft = sigm_(acg[1]), gt = tanh_(acg[2]), ot = sigm_(acg[3]);
    c = ft * c + it * gt;
    h = ot * tanh_(c);

    // ---- normalize e_{t+1}: linear mean (x.wbar + bS) + reduced variance
    float en;
    {
      float s2 = sm.embp[0][0] + sm.embp[1][0];
      v2 mac = XN[0] * WB[0];
      mac = pkfma(XN[1], WB[1], mac);
      mac = pkfma(XN[2], WB[2], mac);
      mac = pkfma(XN[3], WB[3], mac);
      float mn = mac.x + mac.y + bS;
      float vr = fmaf(s2, 0.0078125f, -mn * mn);
      float inv = fast_rsq(vr + 1e-5f);
      en = (en_raw - mn) * inv * egg + ebt + pen;
    }

    // ---- epilogue partials for step t (consumed at next barrier 1)
    {
      float y = h + e;
      float ry0 = wave_sum(y), ry1 = wave_sum(y * y), ry2 = wave_sum(y * a_);
      if (L == 0) { sm.outp[w][0] = ry0; sm.outp[w][1] = ry1; sm.outp[w][2] = ry2; }
    }
    e = en;
  }

  __syncthreads();
  if (tid == 0) {
    float sy  = sm.outp[0][0] + sm.outp[1][0];
    float sy2 = sm.outp[0][1] + sm.outp[1][1];
    float sya = sm.outp[0][2] + sm.outp[1][2];
    float mn2 = sy * 0.0078125f;
    float vr2 = fmaf(sy2, 0.0078125f, -mn2 * mn2);
    float inv2 = fast_rsq(vr2 + 1e-5f);
    out[b * Tv + Tv - 1] = fmaf(inv2, sya - mn2 * SW, KB);
  }
}

extern "C" void kernel_launch(void* const* d_in, const int* in_sizes, int n_in,
                              void* d_out, int out_size, void* d_ws, size_t ws_size,
                              hipStream_t stream) {
  qlstm_kernel<<<dim3(1024), dim3(128), 0, stream>>>(
      (const float*)d_in[0],  (const float*)d_in[1],  (const float*)d_in[2],  (const float*)d_in[3],
      (const float*)d_in[4],  (const float*)d_in[5],  (const float*)d_in[6],  (const float*)d_in[7],
      (const float*)d_in[8],  (const float*)d_in[9],  (const float*)d_in[10], (const float*)d_in[11],
      (const float*)d_in[12], (const float*)d_in[13], (const float*)d_in[14], (const float*)d_in[15],
      (const float*)d_in[16], (const float*)d_in[17], (const float*)d_in[18], (const float*)d_in[19],
      (const float*)d_in[20], (const float*)d_in[21], (const float*)d_in[22], (const float*)d_in[23],
      (const float*)d_in[24], (const float*)d_in[25],
      (float*)d_out);
}

// Round 9
// 464.174 us; speedup vs baseline: 1.0715x; 1.0274x over previous
//
#include <hip/hip_runtime.h>

#define Tv 128

typedef float v2 __attribute__((ext_vector_type(2)));
typedef unsigned uint2v __attribute__((ext_vector_type(2)));

__device__ __forceinline__ v2 pkfma(v2 a, v2 b, v2 c) {
  return __builtin_elementwise_fma(a, b, c);
}

// ---- DPP / cross-lane helpers (builtins only: convergent + hazard-safe)
template<int CTRL>
__device__ __forceinline__ float dppx(float x) {
  return __int_as_float(__builtin_amdgcn_update_dpp(0, __float_as_int(x), CTRL, 0xF, 0xF, true));
}
__device__ __forceinline__ float dpp_rm(float x, int ctrl, int rm) {
  switch (ctrl) {
    default: return 0.f;
    case 0x111: return __int_as_float(__builtin_amdgcn_update_dpp(0, __float_as_int(x), 0x111, 0xF, 0xF, true));
    case 0x112: return __int_as_float(__builtin_amdgcn_update_dpp(0, __float_as_int(x), 0x112, 0xF, 0xF, true));
    case 0x114: return __int_as_float(__builtin_amdgcn_update_dpp(0, __float_as_int(x), 0x114, 0xF, 0xF, true));
    case 0x118: return __int_as_float(__builtin_amdgcn_update_dpp(0, __float_as_int(x), 0x118, 0xF, 0xF, true));
    case 0x142: return __int_as_float(__builtin_amdgcn_update_dpp(0, __float_as_int(x), 0x142, 0xA, 0xF, true));
    case 0x143: return __int_as_float(__builtin_amdgcn_update_dpp(0, __float_as_int(x), 0x143, 0xC, 0xF, true));
  }
}
// full-wave64 sum, broadcast via readlane(63)
__device__ __forceinline__ float wave_sum(float x) {
  x += dpp_rm(x, 0x111, 0xF);
  x += dpp_rm(x, 0x112, 0xF);
  x += dpp_rm(x, 0x114, 0xF);
  x += dpp_rm(x, 0x118, 0xF);
  x += dpp_rm(x, 0x142, 0xA);
  x += dpp_rm(x, 0x143, 0xC);
  return __int_as_float(__builtin_amdgcn_readlane(__float_as_int(x), 63));
}
template<int M>
__device__ __forceinline__ float lane_xor(float x) {
  if constexpr (M == 1)       return dppx<0xB1>(x);    // quad_perm [1,0,3,2]
  else if constexpr (M == 2)  return dppx<0x4E>(x);    // quad_perm [2,3,0,1]
  else if constexpr (M == 8)  return dppx<0x128>(x);   // row_ror:8 == xor8
  else if constexpr (M == 32) return __shfl_xor(x, 32, 64);
  else return __int_as_float(__builtin_amdgcn_ds_swizzle(__float_as_int(x), (M << 10) | 0x1F));
}
// symmetric xor-partner sums via permlane*_swap (VALU pipe, direction-robust:
// with equal inputs the two outputs are {lo-bcast, hi-bcast} in SOME order, so
// their sum == x + xor_partner(x) regardless of swap direction).
__device__ __forceinline__ float psum16(float x) {
  uint2v r = __builtin_amdgcn_permlane16_swap(__float_as_uint(x), __float_as_uint(x), false, false);
  return __uint_as_float(r.x) + __uint_as_float(r.y);
}
__device__ __forceinline__ float psum32(float x) {
  uint2v r = __builtin_amdgcn_permlane32_swap(__float_as_uint(x), __float_as_uint(x), false, false);
  return __uint_as_float(r.x) + __uint_as_float(r.y);
}
__device__ __forceinline__ float bperm(int addr, float x) {
  return __int_as_float(__builtin_amdgcn_ds_bpermute(addr, __float_as_int(x)));
}
__device__ __forceinline__ float rdlane(float x, int l) {
  return __int_as_float(__builtin_amdgcn_readlane(__float_as_int(x), l));
}
__device__ __forceinline__ float fast_rcp(float x){ return __builtin_amdgcn_rcpf(x); }
__device__ __forceinline__ float fast_rsq(float x){ return __builtin_amdgcn_rsqf(x); }
__device__ __forceinline__ float tanh_(float x){
  float e = __expf(2.0f * x);
  return 1.0f - 2.0f * fast_rcp(e + 1.0f);
}
__device__ __forceinline__ float sigm_(float x){
  return fast_rcp(1.0f + __expf(-x));
}

// butterfly transpose-reduce: returns (per lane) the sum over the 64-lane wave
// of element (L&7) of each thread's 8-vector P2 (packed as v2[4]).
// Final symmetric levels use permlane swaps (VALU) instead of swizzle/shfl (LDS).
__device__ __forceinline__ float transpose_reduce8(const v2* P2, int L) {
  const int bb0 = L & 1, bb1 = L & 2, bb2 = L & 4;
  float q_[4];
  #pragma unroll
  for (int k = 0; k < 4; k++) {
    float keep = bb0 ? P2[k].y : P2[k].x;
    float send = bb0 ? P2[k].x : P2[k].y;
    q_[k] = keep + lane_xor<1>(send);
  }
  float r_[2];
  #pragma unroll
  for (int k = 0; k < 2; k++) {
    float keep = bb1 ? q_[2 * k + 1] : q_[2 * k];
    float send = bb1 ? q_[2 * k]     : q_[2 * k + 1];
    r_[k] = keep + lane_xor<2>(send);
  }
  float u;
  {
    float keep = bb2 ? r_[1] : r_[0];
    float send = bb2 ? r_[0] : r_[1];
    u = keep + lane_xor<4>(send);
  }
  u += lane_xor<8>(u);
  u = psum16(u);
  u = psum32(u);
  return u;
}

// tan-form lane RY: S[k] += ts * xor_M(S[k]); ts pre-signed per lane.
template<int M>
__device__ __forceinline__ void ry_lane_t(v2* S, float ts) {
  v2 ts2 = {ts, ts};
  #pragma unroll
  for (int k = 0; k < 4; k++) {
    v2 o;
    o.x = lane_xor<M>(S[k].x);
    o.y = lane_xor<M>(S[k].y);
    S[k] = pkfma(ts2, o, S[k]);
  }
}

// State: 256 amps = 8 regs x 32 lanes, packed as v2 S[4]; s[r] = S[r>>1][r&1].
// q0 -> reg bit2; q1 -> reg bit1; q2 -> reg bit0 (x<->y); q3..q7 -> lane masks 16,8,4,2,1.
// Variational RYs in exact tan(theta/2) form (sequential, R1-verified);
// per-gate (prod cos)^2 applied once to the quadratic z measurements (ct2g).

struct __align__(16) SMem {
  float tt[4][36];    // per gate: tan(theta/2) at [l*8+q], (prod cos)^2 at [32]
  float ipb[8][4];    // (ip_b, in_g*0.5, in_b*0.5, 0)  -> theta/2 computed directly
  float zbuf[32];     // z[gate][qubit]
  float embp[2][2];   // emb partials
  float projp[2][8];  // proj partials (init: wbar partials)
  float outp[2][4];   // out-epilogue partials (init: SW/KB)
};

__global__ __launch_bounds__(128, 2) void qlstm_kernel(
    const float* __restrict__ x,     const float* __restrict__ pe,
    const float* __restrict__ emb_w, const float* __restrict__ emb_b,
    const float* __restrict__ emb_g, const float* __restrict__ emb_bt,
    const float* __restrict__ ip_w,  const float* __restrict__ ip_b,
    const float* __restrict__ in_g,  const float* __restrict__ in_b,
    const float* __restrict__ wq_i,  const float* __restrict__ wq_f,
    const float* __restrict__ wq_gt, const float* __restrict__ wq_o,
    const float* __restrict__ pi_w,  const float* __restrict__ pi_b,
    const float* __restrict__ pf_w,  const float* __restrict__ pf_b,
    const float* __restrict__ pg_w,  const float* __restrict__ pg_b,
    const float* __restrict__ po_w,  const float* __restrict__ po_b,
    const float* __restrict__ on_g,  const float* __restrict__ on_b,
    const float* __restrict__ out_w, const float* __restrict__ out_b,
    float* __restrict__ out)
{
  __shared__ SMem sm;
  const int tid = threadIdx.x;          // 0..127 = row j
  const int b   = blockIdx.x;
  const int w   = tid >> 6;             // wave 0/1
  const int L   = tid & 63;
  const int l5  = L & 31;
  const int gate = w * 2 + (L >> 5);    // 0..3 = i,f,g,o
  const int o8  = L & 7;

  // ---- stage tan table + per-gate cos-product
  {
    int gg = tid >> 5, rem = tid & 31;
    const float* wsel = (gg == 0) ? wq_i : (gg == 1) ? wq_f : (gg == 2) ? wq_gt : wq_o;
    float th = wsel[rem] * 0.5f;
    float cc = __cosf(th), ss = __sinf(th);
    sm.tt[gg][rem] = ss * fast_rcp(cc);
    float v = cc;
    v *= lane_xor<1>(v); v *= lane_xor<2>(v); v *= lane_xor<4>(v);
    v *= lane_xor<8>(v); v *= lane_xor<16>(v);
    if (rem == 0) sm.tt[gg][32] = v * v;
  }
  if (tid < 8) {
    sm.ipb[tid][0] = ip_b[tid];
    sm.ipb[tid][1] = in_g[tid] * 0.5f;
    sm.ipb[tid][2] = in_b[tid] * 0.5f;
    sm.ipb[tid][3] = 0.0f;
  }

  // ---- persistent per-thread weights (row j = tid)
  const int j = tid;
  v2 EW[4];
  {
    float4 a = *reinterpret_cast<const float4*>(emb_w + j * 8);
    float4 c = *reinterpret_cast<const float4*>(emb_w + j * 8 + 4);
    EW[0] = {a.x, a.y}; EW[1] = {a.z, a.w}; EW[2] = {c.x, c.y}; EW[3] = {c.z, c.w};
  }
  float ebb = emb_b[j], egg = emb_g[j], ebt = emb_bt[j];
  v2 IPW1[4], IPW2[4];
  #pragma unroll
  for (int k = 0; k < 4; k++) {
    IPW1[k] = {ip_w[(2 * k) * 256 + j],       ip_w[(2 * k + 1) * 256 + j]};
    IPW2[k] = {ip_w[(2 * k) * 256 + 128 + j], ip_w[(2 * k + 1) * 256 + 128 + j]};
  }
  v2 GW[4][4];
  #pragma unroll
  for (int gg = 0; gg < 4; gg++) {
    const float* pw = (gg == 0) ? pi_w : (gg == 1) ? pf_w : (gg == 2) ? pg_w : po_w;
    float4 a = *reinterpret_cast<const float4*>(pw + j * 8);
    float4 c = *reinterpret_cast<const float4*>(pw + j * 8 + 4);
    GW[gg][0] = {a.x, a.y}; GW[gg][1] = {a.z, a.w};
    GW[gg][2] = {c.x, c.y}; GW[gg][3] = {c.z, c.w};
  }
  float gb[4] = {pi_b[j], pf_b[j], pg_b[j], po_b[j]};
  float ong = on_g[j], onb = on_b[j], ow_ = out_w[j];
  float outb = out_b[0];
  float a_ = ong * ow_;

  // Composed per-layer CNOT permutation (verified R4)
  const int grp = L & 32;
  int aC0, aC1;
  {
    int l1 = l5 ^ ((l5 & 16) >> 1) ^ ((l5 & 4) >> 1);
    int lb = l1 ^ ((l1 & 8) >> 1) ^ ((l1 & 2) >> 1);
    aC0 = (grp | lb) << 2;
    aC1 = (grp | (lb ^ 16)) << 2;
  }

  // sign masks for measure (qubit q3..q7 <-> lane bits 16,8,4,2,1): bit set -> -T
  const int sg16 = (l5 & 16) << 27;
  const int sg8  = (l5 & 8)  << 28;
  const int sg4  = (l5 & 4)  << 29;
  const int sg2  = (l5 & 2)  << 30;
  const int sg1  = (l5 & 1)  << 31;

  float h = 0.f, c = 0.f;
  const float* xbase = x + (size_t)b * Tv * 8;

  // ---- init: column-sum of emb_w (wbar) + sum of emb_b, for linear mean
  {
    float uw = transpose_reduce8(EW, L);
    float eb1 = wave_sum(ebb);
    if (L < 8) sm.projp[w][L] = uw;
    if (L == 0) sm.embp[w][0] = eb1;
  }
  __syncthreads();                              // ===== init barrier A

  // ---- loop-invariant register hoists (LDS -> VGPR, once)
  v2 WB[4]; float bS;
  {
    #pragma unroll
    for (int k = 0; k < 4; k++) {
      WB[k].x = (sm.projp[0][2 * k]     + sm.projp[1][2 * k])     * 0.0078125f;
      WB[k].y = (sm.projp[0][2 * k + 1] + sm.projp[1][2 * k + 1]) * 0.0078125f;
    }
    bS = (sm.embp[0][0] + sm.embp[1][0]) * 0.0078125f;
  }
  float4 ipbv = *reinterpret_cast<float4*>(&sm.ipb[o8][0]);
  v2 LT0[4], LT1[4], LNTS[4];
  float LTS[4][5];
  float ct2g = sm.tt[gate][32];
  {
    const float* tg = sm.tt[gate];
    #pragma unroll
    for (int l = 0; l < 4; l++) {
      float4 qa = *reinterpret_cast<const float4*>(tg + l * 8);
      float4 qb = *reinterpret_cast<const float4*>(tg + l * 8 + 4);
      LT0[l]  = {qa.x, qa.x};
      LT1[l]  = {qa.y, qa.y};
      LNTS[l] = {-qa.z, qa.z};
      float tq[5] = {qa.w, qb.x, qb.y, qb.z, qb.w};
      #pragma unroll
      for (int q = 0; q < 5; q++) {
        int m = 16 >> q;
        LTS[l][q] = (l5 & m) ? tq[q] : -tq[q];
      }
    }
  }

  // ---- pre-loop: e_0 + SW/KB partials
  float e;
  {
    float4 a = *reinterpret_cast<const float4*>(xbase);
    float4 cq = *reinterpret_cast<const float4*>(xbase + 4);
    v2 XT[4] = {{a.x,a.y},{a.z,a.w},{cq.x,cq.y},{cq.z,cq.w}};
    v2 acc = XT[0] * EW[0];
    acc = pkfma(XT[1], EW[1], acc);
    acc = pkfma(XT[2], EW[2], acc);
    acc = pkfma(XT[3], EW[3], acc);
    float er = ebb + acc.x + acc.y;
    float s2 = wave_sum(er * er);
    float r0 = wave_sum(a_), r1 = wave_sum(onb * ow_);
    if (L == 0) {
      sm.embp[w][1] = s2;
      sm.outp[w][0] = r0; sm.outp[w][1] = r1;
    }
    __syncthreads();                            // ===== init barrier B
    v2 mac = XT[0] * WB[0];
    mac = pkfma(XT[1], WB[1], mac);
    mac = pkfma(XT[2], WB[2], mac);
    mac = pkfma(XT[3], WB[3], mac);
    float mn = mac.x + mac.y + bS;
    float s2t = sm.embp[0][1] + sm.embp[1][1];
    float vr = fmaf(s2t, 0.0078125f, -mn * mn);
    float inv = fast_rsq(vr + 1e-5f);
    e = (er - mn) * inv * egg + ebt + pe[j];
  }
  const float SW = sm.outp[0][0] + sm.outp[1][0];
  const float KB = sm.outp[0][1] + sm.outp[1][1] + outb;

  #pragma unroll 1
  for (int t = 0; t < Tv; t++) {
    // ---- prefetch next x,pe
    v2 XN[4]; float pen;
    {
      int tn = (t + 1) & (Tv - 1);
      float4 a = *reinterpret_cast<const float4*>(xbase + tn * 8);
      float4 cq = *reinterpret_cast<const float4*>(xbase + tn * 8 + 4);
      XN[0] = {a.x,a.y}; XN[1] = {a.z,a.w}; XN[2] = {cq.x,cq.y}; XN[3] = {cq.z,cq.w};
      pen = pe[tn * 128 + j];
    }

    // ---- proj: p_o = e*ipw1[o] + h*ipw2[o] (packed), butterfly transpose-reduce
    const v2 e2 = {e, e}, h2 = {h, h};
    v2 P2[4];
    #pragma unroll
    for (int k = 0; k < 4; k++)
      P2[k] = pkfma(e2, IPW1[k], h2 * IPW2[k]);
    float u = transpose_reduce8(P2, L);
    if (L < 8) sm.projp[w][L] = u;
    __syncthreads();                                  // ===== barrier 1
    u += sm.projp[1 - w][o8];
    if (t && tid == 0) {                              // emit out[t-1] (pipelined)
      float sy  = sm.outp[0][0] + sm.outp[1][0];
      float sy2 = sm.outp[0][1] + sm.outp[1][1];
      float sya = sm.outp[0][2] + sm.outp[1][2];
      float mn2 = sy * 0.0078125f;
      float vr2 = fmaf(sy2, 0.0078125f, -mn2 * mn2);
      float inv2 = fast_rsq(vr2 + 1e-5f);
      out[b * Tv + t - 1] = fmaf(inv2, sya - mn2 * SW, KB);
    }

    // ---- angles: tanh + LN(8) -> half-angle directly (ipb pre-scaled by 0.5)
    // xor4 level uses DPP row_ror:4 (== xor4 on lane-period-8 data; no LDS pipe)
    float tv = tanh_(u + ipbv.x);
    float m1 = tv, m2 = tv * tv;
    m1 += lane_xor<1>(m1); m2 += lane_xor<1>(m2);
    m1 += lane_xor<2>(m1); m2 += lane_xor<2>(m2);
    m1 += dppx<0x124>(m1); m2 += dppx<0x124>(m2);
    float pm = m1 * 0.125f;
    float pv = fmaf(m2, 0.125f, -pm * pm);
    float ph = (tv - pm) * fast_rsq(pv + 1e-5f) * ipbv.y + ipbv.z;
    float cE = __cosf(ph), sE = __sinf(ph);
    float fm = cE - sE, fp = cE + sE;
    float f_[16];
    #pragma unroll
    for (int qq = 0; qq < 8; qq++) {
      f_[2 * qq]     = rdlane(fm, qq);
      f_[2 * qq + 1] = rdlane(fp, qq);
    }

    // ---- VQC encode (packed); all f_ reads constant-indexed (no scratch risk)
    v2 S[4];
    {
      float g01_[4];
      #pragma unroll
      for (int i = 0; i < 4; i++)
        g01_[i] = f_[(i >> 1) & 1] * f_[2 + (i & 1)];
      float s3 = (l5 & 16) ? f_[7]  : f_[6];
      float s4 = (l5 & 8)  ? f_[9]  : f_[8];
      float s5 = (l5 & 4)  ? f_[11] : f_[10];
      float s6 = (l5 & 2)  ? f_[13] : f_[12];
      float s7 = (l5 & 1)  ? f_[15] : f_[14];
      float lf = s3 * s4 * s5 * s6 * s7 * 0.0625f;
      const v2 F45 = {f_[4], f_[5]};
      #pragma unroll
      for (int k = 0; k < 4; k++) {
        float tk = lf * g01_[k];
        v2 tk2 = {tk, tk};
        S[k] = tk2 * F45;
      }
    }

    // ---- 4 variational layers: composed bpermute + 8 tan-form RYs each (R1-exact)
    #pragma unroll
    for (int l = 0; l < 4; l++) {
      v2 N0, N1, N2, N3;
      N0.x = bperm(aC0, S[0].x); N0.y = bperm(aC1, S[0].y);
      N1.x = bperm(aC1, S[1].y); N1.y = bperm(aC0, S[1].x);
      N2.x = bperm(aC0, S[3].x); N2.y = bperm(aC1, S[3].y);
      N3.x = bperm(aC1, S[2].y); N3.y = bperm(aC0, S[2].x);
      S[0] = N0; S[1] = N1; S[2] = N2; S[3] = N3;
      // q0: S[k] <-> S[k+2]
      {
        v2 t0 = LT0[l];
        v2 a0 = S[0], a1 = S[1];
        S[0] = pkfma(-t0, S[2], S[0]);
        S[2] = pkfma( t0, a0,  S[2]);
        S[1] = pkfma(-t0, S[3], S[1]);
        S[3] = pkfma( t0, a1,  S[3]);
      }
      // q1: S[k] <-> S[k+1]
      {
        v2 t1 = LT1[l];
        v2 a0 = S[0], a2 = S[2];
        S[0] = pkfma(-t1, S[1], S[0]);
        S[1] = pkfma( t1, a0,  S[1]);
        S[2] = pkfma(-t1, S[3], S[2]);
        S[3] = pkfma( t1, a2,  S[3]);
      }
      // q2: x <-> y
      {
        v2 nts = LNTS[l];
        #pragma unroll
        for (int k = 0; k < 4; k++) {
          v2 aa = S[k];
          v2 sw = __builtin_shufflevector(aa, aa, 1, 0);
          S[k] = pkfma(nts, sw, aa);
        }
      }
      // q3..q7: lane RYs
      ry_lane_t<16>(S, LTS[l][0]);
      ry_lane_t<8>(S, LTS[l][1]);
      ry_lane_t<4>(S, LTS[l][2]);
      ry_lane_t<2>(S, LTS[l][3]);
      ry_lane_t<1>(S, LTS[l][4]);
    }

    // ---- measure: per-lane signed 8-vector, one 32-lane butterfly transpose-reduce
    // V = (z0p, z1p, z2p, +/-T x5); lane l5 ends with z_{l5&7} for its gate.
    {
      v2 P[4];
      #pragma unroll
      for (int k = 0; k < 4; k++) P[k] = S[k] * S[k];
      v2 A = P[0] + P[2];
      v2 B = P[1] + P[3];
      v2 D = (P[0] - P[2]) + (P[1] - P[3]);
      v2 Ev = A - B;
      v2 G = A + B;
      float z0p = D.x + D.y;            // q0 sign: reg bit2
      float z1p = Ev.x + Ev.y;          // q1 sign: reg bit1
      float z2p = G.x - G.y;            // q2 sign: x/y
      float T = G.x + G.y;              // total lane prob
      int Ti = __float_as_int(T);
      v2 ZP[4];
      ZP[0] = {z0p, z1p};
      ZP[1] = {z2p, __int_as_float(Ti ^ sg16)};
      ZP[2] = {__int_as_float(Ti ^ sg8), __int_as_float(Ti ^ sg4)};
      ZP[3] = {__int_as_float(Ti ^ sg2), __int_as_float(Ti ^ sg1)};
      const int cb0 = l5 & 1, cb1 = l5 & 2, cb2 = l5 & 4;
      float mq[4];
      #pragma unroll
      for (int k = 0; k < 4; k++) {
        float keep = cb0 ? ZP[k].y : ZP[k].x;
        float send = cb0 ? ZP[k].x : ZP[k].y;
        mq[k] = keep + lane_xor<1>(send);
      }
      float mr[2];
      #pragma unroll
      for (int k = 0; k < 2; k++) {
        float keep = cb1 ? mq[2 * k + 1] : mq[2 * k];
        float send = cb1 ? mq[2 * k]     : mq[2 * k + 1];
        mr[k] = keep + lane_xor<2>(send);
      }
      float zu;
      {
        float keep = cb2 ? mr[1] : mr[0];
        float send = cb2 ? mr[0] : mr[1];
        zu = keep + lane_xor<4>(send);
      }
      zu += lane_xor<8>(zu);
      zu = psum16(zu);
      if (l5 < 8) sm.zbuf[gate * 8 + l5] = zu * ct2g;
    }

    // ---- next-step emb s2 partial (recurrence-independent; rides barrier 2)
    v2 acc = XN[0] * EW[0];
    acc = pkfma(XN[1], EW[1], acc);
    acc = pkfma(XN[2], EW[2], acc);
    acc = pkfma(XN[3], EW[3], acc);
    float en_raw = ebb + acc.x + acc.y;
    {
      float s2n = wave_sum(en_raw * en_raw);
      if (L == 0) sm.embp[w][0] = s2n;
    }
    __syncthreads();                                  // ===== barrier 2

    // ---- gate projections + LSTM cell (packed dot products)
    float acg[4];
    #pragma unroll
    for (int gg = 0; gg < 4; gg++) {
      float4 za0 = *reinterpret_cast<float4*>(&sm.zbuf[gg * 8]);
      float4 za1 = *reinterpret_cast<float4*>(&sm.zbuf[gg * 8 + 4]);
      v2 Z0 = {za0.x, za0.y}, Z1 = {za0.z, za0.w};
      v2 Z2 = {za1.x, za1.y}, Z3 = {za1.z, za1.w};
      v2 av = Z0 * GW[gg][0];
      av = pkfma(Z1, GW[gg][1], av);
      av = pkfma(Z2, GW[gg][2], av);
      av = pkfma(Z3, GW[gg][3], av);
      acg[gg] = gb[gg] + av.x + av.y;
    }
    float it = sigm_(acg[0]), ft = sigm_(acg[1]), gt = tanh_(acg[2]), ot = sigm_(acg[3]);
    c = ft * c + it * gt;
    h = ot * tanh_(c);

    // ---- normalize e_{t+1}: linear mean (x.wbar + bS) + reduced variance
    float en;
    {
      float s2 = sm.embp[0][0] + sm.embp[1][0];
      v2 mac = XN[0] * WB[0];
      mac = pkfma(XN[1], WB[1], mac);
      mac = pkfma(XN[2], WB[2], mac);
      mac = pkfma(XN[3], WB[3], mac);
      float mn = mac.x + mac.y + bS;
      float vr = fmaf(s2, 0.0078125f, -mn * mn);
      float inv = fast_rsq(vr + 1e-5f);
      en = (en_raw - mn) * inv * egg + ebt + pen;
    }

    // ---- epilogue partials for step t (consumed at next barrier 1)
    {
      float y = h + e;
      float ry0 = wave_sum(y), ry1 = wave_sum(y * y), ry2 = wave_sum(y * a_);
      if (L == 0) { sm.outp[w][0] = ry0; sm.outp[w][1] = ry1; sm.outp[w][2] = ry2; }
    }
    e = en;
  }

  __syncthreads();
  if (tid == 0) {
    float sy  = sm.outp[0][0] + sm.outp[1][0];
    float sy2 = sm.outp[0][1] + sm.outp[1][1];
    float sya = sm.outp[0][2] + sm.outp[1][2];
    float mn2 = sy * 0.0078125f;
    float vr2 = fmaf(sy2, 0.0078125f, -mn2 * mn2);
    float inv2 = fast_rsq(vr2 + 1e-5f);
    out[b * Tv + Tv - 1] = fmaf(inv2, sya - mn2 * SW, KB);
  }
}

extern "C" void kernel_launch(void* const* d_in, const int* in_sizes, int n_in,
                              void* d_out, int out_size, void* d_ws, size_t ws_size,
                              hipStream_t stream) {
  qlstm_kernel<<<dim3(1024), dim3(128), 0, stream>>>(
      (const float*)d_in[0],  (const float*)d_in[1],  (const float*)d_in[2],  (const float*)d_in[3],
      (const float*)d_in[4],  (const float*)d_in[5],  (const float*)d_in[6],  (const float*)d_in[7],
      (const float*)d_in[8],  (const float*)d_in[9],  (const float*)d_in[10], (const float*)d_in[11],
      (const float*)d_in[12], (const float*)d_in[13], (const float*)d_in[14], (const float*)d_in[15],
      (const float*)d_in[16], (const float*)d_in[17], (const float*)d_in[18], (const float*)d_in[19],
      (const float*)d_in[20], (const float*)d_in[21], (const float*)d_in[22], (const float*)d_in[23],
      (const float*)d_in[24], (const float*)d_in[25],
      (float*)d_out);
}